// Round 1
// baseline (4274.608 us; speedup 1.0000x reference)
//
#include <hip/hip_runtime.h>
#include <hip/hip_bf16.h>
#include <stdint.h>

typedef __bf16 bf16_t;
typedef __bf16 bf16x8 __attribute__((ext_vector_type(8)));
typedef __bf16 bf16x4 __attribute__((ext_vector_type(4)));
typedef float  floatx4 __attribute__((ext_vector_type(4)));

#define T_STEPS 128
#define BATCH   64
#define EDIM    1024
#define HDIM    1024
#define VOCAB   10000
#define MROWS   (T_STEPS * BATCH)   // 8192
#define NBLK    64                  // step-kernel grid (<< 256 CUs -> co-resident)

__device__ __forceinline__ floatx4 mfma16(bf16x8 a, bf16x8 b, floatx4 c) {
    return __builtin_amdgcn_mfma_f32_16x16x32_bf16(a, b, c, 0, 0, 0);
}

// ---------------- setup kernels ----------------

__global__ void f2b_kernel(const float* __restrict__ s, bf16_t* __restrict__ d, int n) {
    int i = (blockIdx.x * blockDim.x + threadIdx.x) * 4;
    if (i < n) {
        float4 v = *(const float4*)(s + i);
        bf16x4 o;
        o.x = (bf16_t)v.x; o.y = (bf16_t)v.y; o.z = (bf16_t)v.z; o.w = (bf16_t)v.w;
        *(bf16x4*)(d + i) = o;
    }
}

__global__ void gather_kernel(const float* __restrict__ emb, const int* __restrict__ tok,
                              bf16_t* __restrict__ X) {
    int row = blockIdx.x;                 // 0..8191 == t*B + b
    int t = tok[row];
    int e = threadIdx.x * 4;
    float4 v = *(const float4*)(emb + (size_t)t * EDIM + e);
    bf16x4 o;
    o.x = (bf16_t)v.x; o.y = (bf16_t)v.y; o.z = (bf16_t)v.z; o.w = (bf16_t)v.w;
    *(bf16x4*)(X + (size_t)row * EDIM + e) = o;
}

__global__ void init_state_kernel(const float* __restrict__ hidden,
                                  bf16_t* __restrict__ h0buf, bf16_t* __restrict__ h1all,
                                  int* __restrict__ ctr) {
    int i = blockIdx.x * blockDim.x + threadIdx.x;   // 65536 threads
    h0buf[BATCH * HDIM + i] = (bf16_t)hidden[i];               // h0[-1] -> buf[1]
    h1all[i]                = (bf16_t)hidden[BATCH * HDIM + i]; // h1[-1] -> h1all[0]
    if (i == 0) *ctr = 0;
}

// ---------------- big GEMM: C[M,N] = A[M,K] @ W[N,K]^T + bias ----------------
// 128x128 tile, BK=32, 4 waves (2x2), each wave 4x4 MFMA 16x16x32 tiles.

template <int OUT_BF16>
__global__ __launch_bounds__(256) void gemm_kernel(
    const bf16_t* __restrict__ A, const bf16_t* __restrict__ W,
    const float* __restrict__ bias, void* __restrict__ out,
    int M, int N, int K)
{
    const int tid  = threadIdx.x;
    const int lane = tid & 63;
    const int wave = tid >> 6;
    const int wm   = wave & 1;
    const int wn   = wave >> 1;
    const int quad = lane >> 4;
    const int l16  = lane & 15;
    const int mTile = blockIdx.y * 128;
    const int nTile = blockIdx.x * 128;

    __shared__ bf16_t sA[128 * 32];
    __shared__ bf16_t sW[128 * 32];

    const floatx4 fzero = {0.f, 0.f, 0.f, 0.f};
    floatx4 acc[4][4];
    #pragma unroll
    for (int i = 0; i < 4; ++i)
        #pragma unroll
        for (int j = 0; j < 4; ++j) acc[i][j] = fzero;

    for (int kk = 0; kk < K; kk += 32) {
        __syncthreads();
        #pragma unroll
        for (int j = 0; j < 2; ++j) {
            int c   = tid + j * 256;     // chunk 0..511, 16B each
            int row = c >> 2;            // 0..127
            int sub = c & 3;             // k-offset/8
            int4 va = *(const int4*)(A + (size_t)(mTile + row) * K + kk + sub * 8);
            *(int4*)(sA + c * 8) = va;
            int wrow = nTile + row;
            if (wrow >= N) wrow = N - 1;  // clamp for V=10000 edge tile
            int4 vw = *(const int4*)(W + (size_t)wrow * K + kk + sub * 8);
            *(int4*)(sW + c * 8) = vw;
        }
        __syncthreads();
        bf16x8 af[4], wf[4];
        #pragma unroll
        for (int mi = 0; mi < 4; ++mi)
            af[mi] = *(const bf16x8*)(sA + (wm * 64 + mi * 16 + l16) * 32 + quad * 8);
        #pragma unroll
        for (int ni = 0; ni < 4; ++ni)
            wf[ni] = *(const bf16x8*)(sW + (wn * 64 + ni * 16 + l16) * 32 + quad * 8);
        #pragma unroll
        for (int mi = 0; mi < 4; ++mi)
            #pragma unroll
            for (int ni = 0; ni < 4; ++ni)
                acc[mi][ni] = mfma16(af[mi], wf[ni], acc[mi][ni]);
    }

    #pragma unroll
    for (int ni = 0; ni < 4; ++ni) {
        int col = nTile + wn * 64 + ni * 16 + l16;
        if (col < N) {
            float bv = bias[col];
            #pragma unroll
            for (int mi = 0; mi < 4; ++mi) {
                #pragma unroll
                for (int r = 0; r < 4; ++r) {
                    int row = mTile + wm * 64 + mi * 16 + quad * 4 + r;
                    float v = acc[mi][ni][r] + bv;
                    if (OUT_BF16) ((bf16_t*)out)[(size_t)row * N + col] = (bf16_t)v;
                    else          ((float*)out)[(size_t)row * N + col] = v;
                }
            }
        }
    }
}

// ---------------- sequential RNN: one kernel, spin-barrier phases ----------------
// Phase p: compute h0[p] (p<128) and h1[p-1] (p>=1). Block b owns cols 16b..16b+15.
// Wave w owns rows 16w..16w+15. A-fragments read directly from global (coalesced 64B).

__global__ __launch_bounds__(256) void rnn_step_kernel(
    const bf16_t* __restrict__ X0,     // [8192][1024] = x@W_in0^T + b0
    const bf16_t* __restrict__ Wh0b,
    const bf16_t* __restrict__ Win1b,
    const bf16_t* __restrict__ Wh1b,
    const float*  __restrict__ b1,
    bf16_t* __restrict__ h0buf,        // [2][64][1024] ping-pong
    bf16_t* __restrict__ h1all,        // [129][64][1024]; [0]=h1 init, [t+1]=h1[t]
    int* __restrict__ ctr)
{
    const int tid  = threadIdx.x;
    const int lane = tid & 63;
    const int wave = tid >> 6;
    const int quad = lane >> 4;
    const int l16  = lane & 15;
    const int colg = blockIdx.x * 16 + l16;
    const floatx4 fzero = {0.f, 0.f, 0.f, 0.f};

    const bf16_t* Wh0r  = Wh0b  + (size_t)colg * HDIM;
    const bf16_t* Win1r = Win1b + (size_t)colg * HDIM;
    const bf16_t* Wh1r  = Wh1b  + (size_t)colg * HDIM;
    const float bb = b1[colg];
    const int arow  = (wave * 16 + l16) * HDIM;  // A-fragment row offset
    const int orow0 = wave * 16 + quad * 4;      // C row base

    for (int p = 0; p <= T_STEPS; ++p) {
        if (p < T_STEPS) {
            // h0[p] = tanh(X0[p] + h0[p-1] @ Wh0^T)
            const bf16_t* Ap = h0buf + ((p + 1) & 1) * (BATCH * HDIM);
            floatx4 a0 = fzero, a1 = fzero;
            #pragma unroll 4
            for (int kc = 0; kc < 32; ++kc) {
                int k = kc * 32 + quad * 8;
                bf16x8 av = *(const bf16x8*)(Ap + arow + k);
                bf16x8 wv = *(const bf16x8*)(Wh0r + k);
                if (kc & 1) a1 = mfma16(av, wv, a1);
                else        a0 = mfma16(av, wv, a0);
            }
            bf16_t* dst = h0buf + (p & 1) * (BATCH * HDIM);
            const bf16_t* x0p = X0 + (size_t)p * BATCH * HDIM;
            #pragma unroll
            for (int r = 0; r < 4; ++r) {
                int row = orow0 + r;
                float x = (float)x0p[row * HDIM + colg];
                float v = tanhf(x + a0[r] + a1[r]);
                dst[row * HDIM + colg] = (bf16_t)v;
            }
        }
        if (p >= 1) {
            // h1[t] = tanh(h0[t] @ W_in1^T + h1[t-1] @ Wh1^T + b1), t = p-1
            const int t = p - 1;
            const bf16_t* A0 = h0buf + (t & 1) * (BATCH * HDIM);
            const bf16_t* A1 = h1all + (size_t)t * (BATCH * HDIM);
            floatx4 accA = fzero, accB = fzero;
            #pragma unroll 2
            for (int kc = 0; kc < 32; ++kc) {
                int k = kc * 32 + quad * 8;
                bf16x8 av0 = *(const bf16x8*)(A0 + arow + k);
                bf16x8 wv0 = *(const bf16x8*)(Win1r + k);
                accA = mfma16(av0, wv0, accA);
                bf16x8 av1 = *(const bf16x8*)(A1 + arow + k);
                bf16x8 wv1 = *(const bf16x8*)(Wh1r + k);
                accB = mfma16(av1, wv1, accB);
            }
            bf16_t* dst = h1all + (size_t)p * (BATCH * HDIM);
            #pragma unroll
            for (int r = 0; r < 4; ++r) {
                int row = orow0 + r;
                float v = tanhf(accA[r] + accB[r] + bb);
                dst[row * HDIM + colg] = (bf16_t)v;
            }
        }
        // ---- device-scope grid barrier (64 co-resident blocks) ----
        __syncthreads();
        if (tid == 0) {
            __threadfence();
            __hip_atomic_fetch_add(ctr, 1, __ATOMIC_RELEASE, __HIP_MEMORY_SCOPE_AGENT);
            const int target = NBLK * (p + 1);
            while (__hip_atomic_load(ctr, __ATOMIC_ACQUIRE, __HIP_MEMORY_SCOPE_AGENT) < target) {
                __builtin_amdgcn_s_sleep(1);
            }
            __threadfence();
        }
        __syncthreads();
    }
}

__global__ void finalize_kernel(const bf16_t* __restrict__ h0buf,
                                const bf16_t* __restrict__ h1all,
                                float* __restrict__ out) {
    int i = blockIdx.x * blockDim.x + threadIdx.x;   // 65536 threads
    const size_t OUT0 = (size_t)MROWS * VOCAB;
    // h0[127] lives in buf[127&1]=buf[1]; h1[127] in h1all[128]
    out[OUT0 + i]               = (float)h0buf[BATCH * HDIM + i];
    out[OUT0 + BATCH * HDIM + i] = (float)h1all[(size_t)T_STEPS * BATCH * HDIM + i];
}

// ---------------- launcher ----------------

extern "C" void kernel_launch(void* const* d_in, const int* in_sizes, int n_in,
                              void* d_out, int out_size, void* d_ws, size_t ws_size,
                              hipStream_t stream) {
    (void)in_sizes; (void)n_in; (void)out_size; (void)ws_size;
    const float* emb    = (const float*)d_in[0];
    const float* W_in0  = (const float*)d_in[1];
    const float* Wh0    = (const float*)d_in[2];
    const float* b0     = (const float*)d_in[3];
    const float* W_in1  = (const float*)d_in[4];
    const float* Wh1    = (const float*)d_in[5];
    const float* b1     = (const float*)d_in[6];
    const float* Wdec   = (const float*)d_in[7];
    const float* bdec   = (const float*)d_in[8];
    const float* hidden = (const float*)d_in[9];
    const int*   tokens = (const int*)d_in[10];
    float* out = (float*)d_out;

    char* ws = (char*)d_ws;
    auto alloc = [&](size_t bytes) {
        char* p = ws; ws += (bytes + 255) & ~(size_t)255; return p;
    };
    bf16_t* Xemb  = (bf16_t*)alloc((size_t)MROWS * EDIM * 2);
    bf16_t* X0    = (bf16_t*)alloc((size_t)MROWS * HDIM * 2);
    bf16_t* Win0b = (bf16_t*)alloc((size_t)HDIM * EDIM * 2);
    bf16_t* Wh0b  = (bf16_t*)alloc((size_t)HDIM * HDIM * 2);
    bf16_t* Win1b = (bf16_t*)alloc((size_t)HDIM * HDIM * 2);
    bf16_t* Wh1b  = (bf16_t*)alloc((size_t)HDIM * HDIM * 2);
    bf16_t* Wdecb = (bf16_t*)alloc((size_t)VOCAB * HDIM * 2);
    bf16_t* h1all = (bf16_t*)alloc((size_t)(T_STEPS + 1) * BATCH * HDIM * 2);
    bf16_t* h0buf = (bf16_t*)alloc((size_t)2 * BATCH * HDIM * 2);
    int*    ctr   = (int*)alloc(256);

    f2b_kernel<<<dim3(HDIM * EDIM / 1024), 256, 0, stream>>>(W_in0, Win0b, HDIM * EDIM);
    f2b_kernel<<<dim3(HDIM * HDIM / 1024), 256, 0, stream>>>(Wh0,   Wh0b,  HDIM * HDIM);
    f2b_kernel<<<dim3(HDIM * HDIM / 1024), 256, 0, stream>>>(W_in1, Win1b, HDIM * HDIM);
    f2b_kernel<<<dim3(HDIM * HDIM / 1024), 256, 0, stream>>>(Wh1,   Wh1b,  HDIM * HDIM);
    f2b_kernel<<<dim3(VOCAB * HDIM / 1024), 256, 0, stream>>>(Wdec, Wdecb, VOCAB * HDIM);
    gather_kernel<<<dim3(MROWS), 256, 0, stream>>>(emb, tokens, Xemb);
    init_state_kernel<<<dim3(256), 256, 0, stream>>>(hidden, h0buf, h1all, ctr);

    // X0 = Xemb @ W_in0^T + b0  (bf16 out)
    gemm_kernel<1><<<dim3(HDIM / 128, MROWS / 128), 256, 0, stream>>>(
        Xemb, Win0b, b0, X0, MROWS, HDIM, EDIM);

    rnn_step_kernel<<<dim3(NBLK), 256, 0, stream>>>(
        X0, Wh0b, Win1b, Wh1b, b1, h0buf, h1all, ctr);

    // logits = h1_all @ Wdec^T + bdec  (fp32 out, straight into d_out)
    gemm_kernel<0><<<dim3((VOCAB + 127) / 128, MROWS / 128), 256, 0, stream>>>(
        h1all + BATCH * HDIM, Wdecb, bdec, out, MROWS, VOCAB, HDIM);

    finalize_kernel<<<dim3(256), 256, 0, stream>>>(h0buf, h1all, out);
}

// Round 2
// 2334.845 us; speedup vs baseline: 1.8308x; 1.8308x over previous
//
#include <hip/hip_runtime.h>
#include <hip/hip_bf16.h>
#include <stdint.h>

typedef __bf16 bf16_t;
typedef __bf16 bf16x8 __attribute__((ext_vector_type(8)));
typedef __bf16 bf16x4 __attribute__((ext_vector_type(4)));
typedef float  floatx4 __attribute__((ext_vector_type(4)));

#define T_STEPS 128
#define BATCH   64
#define EDIM    1024
#define HDIM    1024
#define VOCAB   10000
#define MROWS   (T_STEPS * BATCH)   // 8192
#define RNN_BLOCKS 128              // 64 layer-0 + 64 layer-1; all co-resident (<=256 CUs)

__device__ __forceinline__ floatx4 mfma16(bf16x8 a, bf16x8 b, floatx4 c) {
    return __builtin_amdgcn_mfma_f32_16x16x32_bf16(a, b, c, 0, 0, 0);
}

// async global->LDS, 16B per lane. LDS dest must be wave-uniform base + lane*16.
__device__ __forceinline__ void gl_lds16(const bf16_t* g, bf16_t* l) {
    __builtin_amdgcn_global_load_lds(
        (const __attribute__((address_space(1))) void*)g,
        (__attribute__((address_space(3))) void*)l, 16, 0, 0);
}

// ---------------- setup kernels ----------------

__global__ void f2b_kernel(const float* __restrict__ s, bf16_t* __restrict__ d, int n) {
    int i = (blockIdx.x * blockDim.x + threadIdx.x) * 4;
    if (i < n) {
        float4 v = *(const float4*)(s + i);
        bf16x4 o;
        o.x = (bf16_t)v.x; o.y = (bf16_t)v.y; o.z = (bf16_t)v.z; o.w = (bf16_t)v.w;
        *(bf16x4*)(d + i) = o;
    }
}

__global__ void gather_kernel(const float* __restrict__ emb, const int* __restrict__ tok,
                              bf16_t* __restrict__ X) {
    int row = blockIdx.x;
    int t = tok[row];
    int e = threadIdx.x * 4;
    float4 v = *(const float4*)(emb + (size_t)t * EDIM + e);
    bf16x4 o;
    o.x = (bf16_t)v.x; o.y = (bf16_t)v.y; o.z = (bf16_t)v.z; o.w = (bf16_t)v.w;
    *(bf16x4*)(X + (size_t)row * EDIM + e) = o;
}

__global__ void init_state_kernel(const float* __restrict__ hidden,
                                  bf16_t* __restrict__ h0buf, bf16_t* __restrict__ h1all,
                                  int* __restrict__ ctr) {
    int i = blockIdx.x * blockDim.x + threadIdx.x;   // 65536 threads
    h0buf[BATCH * HDIM + i] = (bf16_t)hidden[i];                // h0[-1] -> buf[1]
    h1all[i]                = (bf16_t)hidden[BATCH * HDIM + i]; // h1[-1] -> h1all[0]
    if (i == 0) *ctr = 0;
}

// ---------------- big GEMM: C[M,N] = A[M,K] @ W[N,K]^T + bias ----------------
// 128x128 tile, BK=32, 4 waves (2x2), 4x4 MFMA 16x16x32 per wave.
// Staging via global_load_lds width=16 (m97 pattern).

template <int OUT_BF16>
__global__ __launch_bounds__(256) void gemm_kernel(
    const bf16_t* __restrict__ A, const bf16_t* __restrict__ W,
    const float* __restrict__ bias, void* __restrict__ out,
    int M, int N, int K)
{
    const int tid  = threadIdx.x;
    const int lane = tid & 63;
    const int wave = tid >> 6;
    const int wm   = wave & 1;
    const int wn   = wave >> 1;
    const int quad = lane >> 4;
    const int l16  = lane & 15;
    const int mTile = blockIdx.y * 128;
    const int nTile = blockIdx.x * 128;

    __shared__ __align__(16) bf16_t sA[128 * 32];
    __shared__ __align__(16) bf16_t sW[128 * 32];

    const floatx4 fzero = {0.f, 0.f, 0.f, 0.f};
    floatx4 acc[4][4];
    #pragma unroll
    for (int i = 0; i < 4; ++i)
        #pragma unroll
        for (int j = 0; j < 4; ++j) acc[i][j] = fzero;

    for (int kk = 0; kk < K; kk += 32) {
        __syncthreads();
        #pragma unroll
        for (int j = 0; j < 2; ++j) {
            int c   = tid + j * 256;     // chunk 0..511, 16B each; LDS dst = c*16 bytes
            int row = c >> 2;
            int sub = c & 3;
            gl_lds16(A + (size_t)(mTile + row) * K + kk + sub * 8, sA + c * 8);
            int wrow = nTile + row;
            if (wrow >= N) wrow = N - 1;  // clamp for V=10000 edge tile
            gl_lds16(W + (size_t)wrow * K + kk + sub * 8, sW + c * 8);
        }
        __syncthreads();                 // compiler drains vmcnt before s_barrier
        bf16x8 af[4], wf[4];
        #pragma unroll
        for (int mi = 0; mi < 4; ++mi)
            af[mi] = *(const bf16x8*)(sA + (wm * 64 + mi * 16 + l16) * 32 + quad * 8);
        #pragma unroll
        for (int ni = 0; ni < 4; ++ni)
            wf[ni] = *(const bf16x8*)(sW + (wn * 64 + ni * 16 + l16) * 32 + quad * 8);
        #pragma unroll
        for (int mi = 0; mi < 4; ++mi)
            #pragma unroll
            for (int ni = 0; ni < 4; ++ni)
                acc[mi][ni] = mfma16(af[mi], wf[ni], acc[mi][ni]);
    }

    #pragma unroll
    for (int ni = 0; ni < 4; ++ni) {
        int col = nTile + wn * 64 + ni * 16 + l16;
        if (col < N) {
            float bv = bias[col];
            #pragma unroll
            for (int mi = 0; mi < 4; ++mi) {
                #pragma unroll
                for (int r = 0; r < 4; ++r) {
                    int row = mTile + wm * 64 + mi * 16 + quad * 4 + r;
                    float v = acc[mi][ni][r] + bv;
                    if (OUT_BF16) ((bf16_t*)out)[(size_t)row * N + col] = (bf16_t)v;
                    else          ((float*)out)[(size_t)row * N + col] = v;
                }
            }
        }
    }
}

// ---------------- sequential RNN ----------------
// 128 blocks: 0..63 layer-0 (h0, Wh0 slice in LDS 32KB), 64..127 layer-1
// (h1, Win1+Wh1 slices in LDS 64KB). Block owns 16 output cols. Phase p:
// L0 computes h0[p], L1 computes h1[p-1]. Weights live in LDS (immune to the
// per-phase L2 invalidate). Spin uses RELAXED polls (no buffer_inv storm);
// exactly one release-wbl2 + one acquire-inv per block per phase.
// LDS weight layout: chunk c=(kc,lane): W[cbase+(lane&15)][kc*32+(lane>>4)*8..+7]
// at byte offset c*16 -> ds_read_b128 at lane*16 (conflict-free).

__global__ __launch_bounds__(256, 1) void rnn_step_kernel(
    const bf16_t* __restrict__ X0,     // [8192][1024] = x@W_in0^T + b0
    const bf16_t* __restrict__ Wh0b,
    const bf16_t* __restrict__ Win1b,
    const bf16_t* __restrict__ Wh1b,
    const float*  __restrict__ b1,
    bf16_t* __restrict__ h0buf,        // [2][64][1024] ping-pong
    bf16_t* __restrict__ h1all,        // [129][64][1024]
    int* __restrict__ ctr)
{
    __shared__ __align__(16) char smem[65536];
    const int tid  = threadIdx.x;
    const int lane = tid & 63;
    const int wave = tid >> 6;
    const int quad = lane >> 4;
    const int l16  = lane & 15;
    const bool isL1 = blockIdx.x >= 64;
    const int cbase = (blockIdx.x & 63) * 16;
    const int colg  = cbase + l16;
    const int arow  = (wave * 16 + l16) * HDIM;
    const int orow0 = wave * 16 + quad * 4;
    const floatx4 fzero = {0.f, 0.f, 0.f, 0.f};

    // ---- stage weight slices into LDS (once) ----
    {
        const bf16_t* W0 = isL1 ? Win1b : Wh0b;
        for (int c = tid; c < 2048; c += 256) {
            int kc2 = c >> 6, ln = c & 63;
            const bf16_t* src = W0 + (size_t)(cbase + (ln & 15)) * HDIM + kc2 * 32 + (ln >> 4) * 8;
            *(int4*)(smem + c * 16) = *(const int4*)src;
        }
        if (isL1) {
            for (int c = tid; c < 2048; c += 256) {
                int kc2 = c >> 6, ln = c & 63;
                const bf16_t* src = Wh1b + (size_t)(cbase + (ln & 15)) * HDIM + kc2 * 32 + (ln >> 4) * 8;
                *(int4*)(smem + 32768 + c * 16) = *(const int4*)src;
            }
        }
    }
    __syncthreads();

    const float bb = isL1 ? b1[colg] : 0.f;

    float xr[4];
    if (!isL1) {
        #pragma unroll
        for (int r = 0; r < 4; ++r)
            xr[r] = (float)X0[(size_t)(orow0 + r) * HDIM + colg];   // phase 0
    }

    for (int p = 0; p <= T_STEPS; ++p) {
        if (!isL1) {
            if (p < T_STEPS) {
                // h0[p] = tanh(X0[p] + h0[p-1] @ Wh0^T)
                const bf16_t* Ap = h0buf + ((p + 1) & 1) * (BATCH * HDIM);
                bf16x8 av[32];
                #pragma unroll
                for (int kc = 0; kc < 32; ++kc)
                    av[kc] = *(const bf16x8*)(Ap + arow + kc * 32 + quad * 8);
                floatx4 a0 = fzero, a1 = fzero;
                #pragma unroll
                for (int kc = 0; kc < 32; ++kc) {
                    bf16x8 wv = *(const bf16x8*)(smem + kc * 1024 + lane * 16);
                    if (kc & 1) a1 = mfma16(av[kc], wv, a1);
                    else        a0 = mfma16(av[kc], wv, a0);
                }
                bf16_t* dst = h0buf + (p & 1) * (BATCH * HDIM);
                #pragma unroll
                for (int r = 0; r < 4; ++r)
                    dst[(orow0 + r) * HDIM + colg] = (bf16_t)tanhf(xr[r] + a0[r] + a1[r]);
                if (p + 1 < T_STEPS) {   // prefetch next X0 (read-only, overlaps barrier)
                    #pragma unroll
                    for (int r = 0; r < 4; ++r)
                        xr[r] = (float)X0[((size_t)(p + 1) * BATCH + orow0 + r) * HDIM + colg];
                }
            }
        } else {
            if (p >= 1) {
                // h1[t] = tanh(h0[t] @ W_in1^T + h1[t-1] @ Wh1^T + b1), t = p-1
                const int t = p - 1;
                const bf16_t* A0 = h0buf + (t & 1) * (BATCH * HDIM);
                const bf16_t* A1 = h1all + (size_t)t * (BATCH * HDIM);
                bf16x8 av0[32], av1[32];
                #pragma unroll
                for (int kc = 0; kc < 32; ++kc) {
                    av0[kc] = *(const bf16x8*)(A0 + arow + kc * 32 + quad * 8);
                    av1[kc] = *(const bf16x8*)(A1 + arow + kc * 32 + quad * 8);
                }
                floatx4 aA = fzero, aB = fzero;
                #pragma unroll
                for (int kc = 0; kc < 32; ++kc) {
                    bf16x8 wv1 = *(const bf16x8*)(smem + kc * 1024 + lane * 16);
                    bf16x8 wv2 = *(const bf16x8*)(smem + 32768 + kc * 1024 + lane * 16);
                    aA = mfma16(av0[kc], wv1, aA);
                    aB = mfma16(av1[kc], wv2, aB);
                }
                bf16_t* dst = h1all + (size_t)p * (BATCH * HDIM);
                #pragma unroll
                for (int r = 0; r < 4; ++r)
                    dst[(orow0 + r) * HDIM + colg] = (bf16_t)tanhf(aA[r] + aB[r] + bb);
            }
        }
        if (p == T_STEPS) break;   // last phase: no barrier, kernel end flushes

        // ---- grid barrier: one wbl2 (release RMW) + relaxed spin + one inv ----
        __syncthreads();           // all waves' stores are in L2 (vmcnt drained)
        if (tid == 0) {
            __hip_atomic_fetch_add(ctr, 1, __ATOMIC_RELEASE, __HIP_MEMORY_SCOPE_AGENT);
            const int target = RNN_BLOCKS * (p + 1);
            while (__hip_atomic_load(ctr, __ATOMIC_RELAXED, __HIP_MEMORY_SCOPE_AGENT) < target)
                __builtin_amdgcn_s_sleep(2);
            (void)__hip_atomic_load(ctr, __ATOMIC_ACQUIRE, __HIP_MEMORY_SCOPE_AGENT);
        }
        __syncthreads();
    }
}

__global__ void finalize_kernel(const bf16_t* __restrict__ h0buf,
                                const bf16_t* __restrict__ h1all,
                                float* __restrict__ out) {
    int i = blockIdx.x * blockDim.x + threadIdx.x;   // 65536 threads
    const size_t OUT0 = (size_t)MROWS * VOCAB;
    out[OUT0 + i]                = (float)h0buf[BATCH * HDIM + i];               // h0[127]
    out[OUT0 + BATCH * HDIM + i] = (float)h1all[(size_t)T_STEPS * BATCH * HDIM + i]; // h1[127]
}

// ---------------- launcher ----------------

extern "C" void kernel_launch(void* const* d_in, const int* in_sizes, int n_in,
                              void* d_out, int out_size, void* d_ws, size_t ws_size,
                              hipStream_t stream) {
    (void)in_sizes; (void)n_in; (void)out_size; (void)ws_size;
    const float* emb    = (const float*)d_in[0];
    const float* W_in0  = (const float*)d_in[1];
    const float* Wh0    = (const float*)d_in[2];
    const float* b0     = (const float*)d_in[3];
    const float* W_in1  = (const float*)d_in[4];
    const float* Wh1    = (const float*)d_in[5];
    const float* b1     = (const float*)d_in[6];
    const float* Wdec   = (const float*)d_in[7];
    const float* bdec   = (const float*)d_in[8];
    const float* hidden = (const float*)d_in[9];
    const int*   tokens = (const int*)d_in[10];
    float* out = (float*)d_out;

    char* ws = (char*)d_ws;
    auto alloc = [&](size_t bytes) {
        char* p = ws; ws += (bytes + 255) & ~(size_t)255; return p;
    };
    bf16_t* Xemb  = (bf16_t*)alloc((size_t)MROWS * EDIM * 2);
    bf16_t* X0    = (bf16_t*)alloc((size_t)MROWS * HDIM * 2);
    bf16_t* Win0b = (bf16_t*)alloc((size_t)HDIM * EDIM * 2);
    bf16_t* Wh0b  = (bf16_t*)alloc((size_t)HDIM * HDIM * 2);
    bf16_t* Win1b = (bf16_t*)alloc((size_t)HDIM * HDIM * 2);
    bf16_t* Wh1b  = (bf16_t*)alloc((size_t)HDIM * HDIM * 2);
    bf16_t* Wdecb = (bf16_t*)alloc((size_t)VOCAB * HDIM * 2);
    bf16_t* h1all = (bf16_t*)alloc((size_t)(T_STEPS + 1) * BATCH * HDIM * 2);
    bf16_t* h0buf = (bf16_t*)alloc((size_t)2 * BATCH * HDIM * 2);
    int*    ctr   = (int*)alloc(256);

    f2b_kernel<<<dim3(HDIM * EDIM / 1024), 256, 0, stream>>>(W_in0, Win0b, HDIM * EDIM);
    f2b_kernel<<<dim3(HDIM * HDIM / 1024), 256, 0, stream>>>(Wh0,   Wh0b,  HDIM * HDIM);
    f2b_kernel<<<dim3(HDIM * HDIM / 1024), 256, 0, stream>>>(W_in1, Win1b, HDIM * HDIM);
    f2b_kernel<<<dim3(HDIM * HDIM / 1024), 256, 0, stream>>>(Wh1,   Wh1b,  HDIM * HDIM);
    f2b_kernel<<<dim3(VOCAB * HDIM / 1024), 256, 0, stream>>>(Wdec, Wdecb, VOCAB * HDIM);
    gather_kernel<<<dim3(MROWS), 256, 0, stream>>>(emb, tokens, Xemb);
    init_state_kernel<<<dim3(256), 256, 0, stream>>>(hidden, h0buf, h1all, ctr);

    // X0 = Xemb @ W_in0^T + b0  (bf16 out)
    gemm_kernel<1><<<dim3(HDIM / 128, MROWS / 128), 256, 0, stream>>>(
        Xemb, Win0b, b0, X0, MROWS, HDIM, EDIM);

    rnn_step_kernel<<<dim3(RNN_BLOCKS), 256, 0, stream>>>(
        X0, Wh0b, Win1b, Wh1b, b1, h0buf, h1all, ctr);

    // logits = h1_all @ Wdec^T + bdec  (fp32 out, straight into d_out)
    gemm_kernel<0><<<dim3((VOCAB + 127) / 128, MROWS / 128), 256, 0, stream>>>(
        h1all + BATCH * HDIM, Wdecb, bdec, out, MROWS, VOCAB, HDIM);

    finalize_kernel<<<dim3(256), 256, 0, stream>>>(h0buf, h1all, out);
}